// Round 3
// baseline (322.739 us; speedup 1.0000x reference)
//
#include <hip/hip_runtime.h>

#define HH_EPS 1e-8f

constexpr int D      = 2048;            // feature dim
constexpr int K      = 16;              // number of reflections
constexpr int R      = 2;               // rows per wave (h state = 64 VGPRs)
constexpr int CHUNKS = D / (64 * 4);    // 8 float4 chunks per lane per row
constexpr int NROWS  = 4 * 4096;        // B * S = 16384

// Prologue: c[k] = 2 / max(dot(v_k, v_k), EPS). One wave per vector.
__global__ void __launch_bounds__(64) hh_norms_kernel(const float* __restrict__ vecs,
                                                      float* __restrict__ c) {
    int k = blockIdx.x;
    int lane = threadIdx.x;           // 0..63
    const float4* v4 = (const float4*)(vecs + k * D);
    float s = 0.f;
#pragma unroll
    for (int j = 0; j < CHUNKS; ++j) {
        float4 v = v4[j * 64 + lane];
        s += v.x * v.x + v.y * v.y + v.z * v.z + v.w * v.w;
    }
#pragma unroll
    for (int off = 32; off >= 1; off >>= 1)
        s += __shfl_xor(s, off);
    if (lane == 0) c[k] = 2.0f / fmaxf(s, HH_EPS);
}

// Each wave owns R=2 rows of h in registers across all K reflections.
// K-loop FULLY unrolled: straight-line code, no loop-carried PHIs -> the
// register allocator keeps h resident (R1's loop-carried 128-float array
// spilled to scratch at VGPR_Count=112 and scratch-L2 traffic dominated).
// launch_bounds(256,4): 128-VGPR budget, 4 waves/SIMD for latency hiding.
__global__ void __launch_bounds__(256, 4) hh_apply_kernel(const float* __restrict__ h_in,
                                                          const float* __restrict__ vecs,
                                                          const float* __restrict__ c,
                                                          float* __restrict__ h_out) {
    int wave = (int)((blockIdx.x * blockDim.x + threadIdx.x) >> 6);
    int lane = threadIdx.x & 63;
    int base_row = wave * R;

    // Load R rows into registers: coalesced float4 loads (1 KiB/chunk/wave).
    float4 h[R][CHUNKS];
#pragma unroll
    for (int r = 0; r < R; ++r) {
        const float4* row = (const float4*)(h_in + (size_t)(base_row + r) * D);
#pragma unroll
        for (int j = 0; j < CHUNKS; ++j)
            h[r][j] = row[j * 64 + lane];
    }

    const float4* v4base = (const float4*)vecs;

#pragma unroll
    for (int k = 0; k < K; ++k) {
        // Load v_k: 8 independent 16B loads issued back-to-back, one wait.
        const float4* vk = v4base + k * (D / 4);
        float4 v[CHUNKS];
#pragma unroll
        for (int j = 0; j < CHUNKS; ++j)
            v[j] = vk[j * 64 + lane];

        float ck = c[k];              // uniform s_load, needed only post-reduce

        // Per-lane partial dots for R rows.
        float dot[R];
#pragma unroll
        for (int r = 0; r < R; ++r) dot[r] = 0.f;
#pragma unroll
        for (int j = 0; j < CHUNKS; ++j) {
#pragma unroll
            for (int r = 0; r < R; ++r) {
                dot[r] += h[r][j].x * v[j].x + h[r][j].y * v[j].y
                        + h[r][j].z * v[j].z + h[r][j].w * v[j].w;
            }
        }

        // Wave-wide butterfly reduction; all lanes end with full sums.
#pragma unroll
        for (int off = 32; off >= 1; off >>= 1) {
#pragma unroll
            for (int r = 0; r < R; ++r)
                dot[r] += __shfl_xor(dot[r], off);
        }

        float t[R];
#pragma unroll
        for (int r = 0; r < R; ++r) t[r] = ck * dot[r];

        // Rank-1 update from registers.
#pragma unroll
        for (int j = 0; j < CHUNKS; ++j) {
#pragma unroll
            for (int r = 0; r < R; ++r) {
                h[r][j].x -= t[r] * v[j].x;
                h[r][j].y -= t[r] * v[j].y;
                h[r][j].z -= t[r] * v[j].z;
                h[r][j].w -= t[r] * v[j].w;
            }
        }
    }

    // Write back.
#pragma unroll
    for (int r = 0; r < R; ++r) {
        float4* row = (float4*)(h_out + (size_t)(base_row + r) * D);
#pragma unroll
        for (int j = 0; j < CHUNKS; ++j)
            row[j * 64 + lane] = h[r][j];
    }
}

extern "C" void kernel_launch(void* const* d_in, const int* in_sizes, int n_in,
                              void* d_out, int out_size, void* d_ws, size_t ws_size,
                              hipStream_t stream) {
    const float* h    = (const float*)d_in[0];   // [4,4096,2048] fp32
    const float* vecs = (const float*)d_in[1];   // [16,2048] fp32
    float* out        = (float*)d_out;           // [4,4096,2048] fp32
    float* c          = (float*)d_ws;            // 16 floats scratch

    hh_norms_kernel<<<K, 64, 0, stream>>>(vecs, c);

    int waves  = NROWS / R;                      // 8192 waves
    int blocks = waves * 64 / 256;               // 2048 blocks of 4 waves
    hh_apply_kernel<<<blocks, 256, 0, stream>>>(h, vecs, c, out);
}

// Round 4
// 318.290 us; speedup vs baseline: 1.0140x; 1.0140x over previous
//
#include <hip/hip_runtime.h>

#define HH_EPS 1e-8f

constexpr int D      = 2048;            // feature dim
constexpr int K      = 16;              // number of reflections
constexpr int R      = 2;               // rows per wave (h state = 64 VGPRs)
constexpr int CHUNKS = D / (64 * 4);    // 8 float4 chunks per lane per row
constexpr int NROWS  = 4 * 4096;        // B * S = 16384

// Prologue: c[k] = 2 / max(dot(v_k, v_k), EPS). One wave per vector.
__global__ void __launch_bounds__(64) hh_norms_kernel(const float* __restrict__ vecs,
                                                      float* __restrict__ c) {
    int k = blockIdx.x;
    int lane = threadIdx.x;           // 0..63
    const float4* v4 = (const float4*)(vecs + k * D);
    float s = 0.f;
#pragma unroll
    for (int j = 0; j < CHUNKS; ++j) {
        float4 v = v4[j * 64 + lane];
        s += v.x * v.x + v.y * v.y + v.z * v.z + v.w * v.w;
    }
#pragma unroll
    for (int off = 32; off >= 1; off >>= 1)
        s += __shfl_xor(s, off);
    if (lane == 0) c[k] = 2.0f / fmaxf(s, HH_EPS);
}

// Each wave owns R=2 rows of h in registers across all K reflections.
//
// R3 post-mortem: with __launch_bounds__(256,4) the allocator chose the
// 8-waves/EU occupancy point (VGPR=64) and spilled ~45 regs of h to scratch
// -> HBM (WRITE_SIZE 267 MB vs 131 MB ideal). launch_bounds' 2nd arg is only
// a MINIMUM; the scheduler's memory-bound heuristic maximized occupancy and
// paid with spills. amdgpu_waves_per_eu(4,4) pins min=max=4 waves/EU:
// VGPR budget exactly 128, no incentive to spill. State ~112 regs fits.
__global__ void __launch_bounds__(256)
__attribute__((amdgpu_waves_per_eu(4, 4)))
hh_apply_kernel(const float* __restrict__ h_in,
                const float* __restrict__ vecs,
                const float* __restrict__ c,
                float* __restrict__ h_out) {
    int wave = (int)((blockIdx.x * blockDim.x + threadIdx.x) >> 6);
    int lane = threadIdx.x & 63;
    int base_row = wave * R;

    // Load R rows into registers: coalesced float4 loads (1 KiB/chunk/wave).
    float4 h[R][CHUNKS];
#pragma unroll
    for (int r = 0; r < R; ++r) {
        const float4* row = (const float4*)(h_in + (size_t)(base_row + r) * D);
#pragma unroll
        for (int j = 0; j < CHUNKS; ++j)
            h[r][j] = row[j * 64 + lane];
    }

    const float4* v4base = (const float4*)vecs;

#pragma unroll
    for (int k = 0; k < K; ++k) {
        // Load v_k: 8 independent 16B loads issued back-to-back, one wait.
        const float4* vk = v4base + k * (D / 4);
        float4 v[CHUNKS];
#pragma unroll
        for (int j = 0; j < CHUNKS; ++j)
            v[j] = vk[j * 64 + lane];

        float ck = c[k];              // uniform s_load, needed only post-reduce

        // Per-lane partial dots for R rows.
        float dot[R];
#pragma unroll
        for (int r = 0; r < R; ++r) dot[r] = 0.f;
#pragma unroll
        for (int j = 0; j < CHUNKS; ++j) {
#pragma unroll
            for (int r = 0; r < R; ++r) {
                dot[r] += h[r][j].x * v[j].x + h[r][j].y * v[j].y
                        + h[r][j].z * v[j].z + h[r][j].w * v[j].w;
            }
        }

        // Wave-wide butterfly reduction; all lanes end with full sums.
#pragma unroll
        for (int off = 32; off >= 1; off >>= 1) {
#pragma unroll
            for (int r = 0; r < R; ++r)
                dot[r] += __shfl_xor(dot[r], off);
        }

        float t[R];
#pragma unroll
        for (int r = 0; r < R; ++r) t[r] = ck * dot[r];

        // Rank-1 update from registers.
#pragma unroll
        for (int j = 0; j < CHUNKS; ++j) {
#pragma unroll
            for (int r = 0; r < R; ++r) {
                h[r][j].x -= t[r] * v[j].x;
                h[r][j].y -= t[r] * v[j].y;
                h[r][j].z -= t[r] * v[j].z;
                h[r][j].w -= t[r] * v[j].w;
            }
        }
    }

    // Write back.
#pragma unroll
    for (int r = 0; r < R; ++r) {
        float4* row = (float4*)(h_out + (size_t)(base_row + r) * D);
#pragma unroll
        for (int j = 0; j < CHUNKS; ++j)
            row[j * 64 + lane] = h[r][j];
    }
}

extern "C" void kernel_launch(void* const* d_in, const int* in_sizes, int n_in,
                              void* d_out, int out_size, void* d_ws, size_t ws_size,
                              hipStream_t stream) {
    const float* h    = (const float*)d_in[0];   // [4,4096,2048] fp32
    const float* vecs = (const float*)d_in[1];   // [16,2048] fp32
    float* out        = (float*)d_out;           // [4,4096,2048] fp32
    float* c          = (float*)d_ws;            // 16 floats scratch

    hh_norms_kernel<<<K, 64, 0, stream>>>(vecs, c);

    int waves  = NROWS / R;                      // 8192 waves
    int blocks = waves * 64 / 256;               // 2048 blocks of 4 waves
    hh_apply_kernel<<<blocks, 256, 0, stream>>>(h, vecs, c, out);
}